// Round 7
// baseline (192.927 us; speedup 1.0000x reference)
//
#include <hip/hip_runtime.h>
#include <math.h>

#define N 8192
#define H 128
#define NEV 64
#define SS 20
#define MAXD 512
#define MAXDIRTY 128
#define RPB 32

// ---------------------------------------------------------------------------
// k_init: fu[n] = first updater-slot id (slot = e*2+i; i=0 -> row v[e],
// i=1 -> row u[e]); zsrc[slot] = canonical slot if node updated before event e
// else -1; wslot[slot] = canonical slot; dtv[slot] = precomputed dt.
// Zeroes deg/dcnt/needh.   [byte-identical to round 6 — passed twice]
// ---------------------------------------------------------------------------
__global__ __launch_bounds__(256) void k_init(
    const int* __restrict__ u, const int* __restrict__ v,
    const float* __restrict__ t, const float* __restrict__ lastt,
    int* __restrict__ fu, int* __restrict__ zsrc, int* __restrict__ wslot,
    float* __restrict__ dtv, int* __restrict__ deg, int* __restrict__ dcnt,
    int* __restrict__ needh)
{
    __shared__ int fuL[N];   // 32 KB
    const int tid = threadIdx.x;
    for (int i = tid; i < N; i += 256) fuL[i] = 0x7FFFFFFF;
    if (tid < 128) { deg[tid] = 0; dcnt[tid] = 0; }
    if (tid < NEV) needh[tid] = 0;
    __syncthreads();
    if (tid < 2 * NEV) {
        const int e = tid >> 1, i = tid & 1;
        const int node = i ? u[e] : v[e];       // i=0 -> row v, i=1 -> row u
        atomicMin(&fuL[node], tid);
    }
    __syncthreads();
    for (int i = tid; i < N; i += 256) fu[i] = fuL[i];
    if (tid < 2 * NEV) {
        const int e = tid >> 1, i = tid & 1;
        const int node = i ? u[e] : v[e];
        const int f = fuL[node];
        wslot[tid] = f;
        zsrc[tid] = (f < 2 * e) ? f : -1;       // updated strictly before event e?
        const int dtn = i ? v[e] : u[e];        // crossed: row v uses let[u], row u let[v]
        int pt = -1;
        for (int e2 = e - 1; e2 >= 0; --e2)
            if (u[e2] == dtn || v[e2] == dtn) { pt = e2; break; }
        const float lv = (pt >= 0) ? t[pt] : lastt[dtn];
        dtv[tid] = t[e] - lv;
    }
}

// ---------------------------------------------------------------------------
// k_emb: h_tab = emb @ W_h.T + b_h ; z_out = emb copy ; d0/d1 rate dots.
// [byte-identical to round 6]
// ---------------------------------------------------------------------------
__global__ __launch_bounds__(512) void k_emb(
    const float* __restrict__ emb, const float* __restrict__ W_h,
    const float* __restrict__ b_h, const float* __restrict__ W_om,
    float* __restrict__ h_tab, float* __restrict__ z_out,
    float* __restrict__ d0, float* __restrict__ d1)
{
    const int tid = threadIdx.x;
    const int c = tid & 127;
    const int s = tid >> 7;             // 0..3
    const int r0 = blockIdx.x * RPB;

    __shared__ __align__(16) float z4[4 * 128];
    __shared__ float pr[8 * 128];

    float whr[32];
#pragma unroll
    for (int i = 0; i < 32; ++i) whr[i] = W_h[c * H + s * 32 + i];
    const float bh_c = b_h[c];

    const int lane = tid & 63;
    const int wid = tid >> 6;
    const int kof = (wid >= 4) ? 256 : 0;
    const float wk_l = W_om[kof + lane]      + W_om[kof + 128 + lane];
    const float wk_h = W_om[kof + 64 + lane] + W_om[kof + 192 + lane];

    for (int b = 0; b < RPB / 4; ++b) {
        const int rbase = r0 + b * 4;
        __syncthreads();
        const float zv = emb[(size_t)rbase * H + tid];
        z4[tid] = zv;
        z_out[(size_t)rbase * H + tid] = zv;
        __syncthreads();

#pragma unroll
        for (int rr = 0; rr < 4; ++rr) {
            float a = 0.f;
#pragma unroll
            for (int i4 = 0; i4 < 8; ++i4) {
                const float4 zz = *(const float4*)&z4[rr * 128 + s * 32 + i4 * 4];
                a += zz.x * whr[i4 * 4] + zz.y * whr[i4 * 4 + 1] +
                     zz.z * whr[i4 * 4 + 2] + zz.w * whr[i4 * 4 + 3];
            }
            pr[(s * 4 + rr) * 128 + c] = a;
        }
        {
            const int rr = wid & 3;
            float val = z4[rr * 128 + lane] * wk_l + z4[rr * 128 + 64 + lane] * wk_h;
#pragma unroll
            for (int off = 32; off > 0; off >>= 1) val += __shfl_xor(val, off);
            if (lane == 0) {
                if (wid < 4) d0[rbase + rr] = val;
                else         d1[rbase + rr] = val;
            }
        }
        __syncthreads();
        {
            const int rr = s;
            const float h = pr[(0 * 4 + rr) * 128 + c] + pr[(1 * 4 + rr) * 128 + c] +
                            pr[(2 * 4 + rr) * 128 + c] + pr[(3 * 4 + rr) * 128 + c] + bh_c;
            h_tab[(size_t)(rbase + rr) * H + c] = h;
        }
    }
}

// ---------------------------------------------------------------------------
// k_nbr: compact neighbor lists for the 128 (event,side) rows.
// [byte-identical to round 6]
// ---------------------------------------------------------------------------
__global__ __launch_bounds__(256) void k_nbr(
    const int* __restrict__ u, const int* __restrict__ v,
    const float* __restrict__ A, const float* __restrict__ S,
    int* __restrict__ deg, float* __restrict__ sumv,
    int* __restrict__ nbr_i, float* __restrict__ nbr_e)
{
    const int slot = blockIdx.x;
    const int e = slot >> 1, side = slot & 1;
    const int row = (side == 0) ? v[e] : u[e];
    const size_t base = (size_t)row * N;
    const int tid = threadIdx.x;
    float lsum = 0.f;
    for (int j = tid; j < N; j += 256) {
        if (A[base + j] > 0.f) {
            const float ev = expf(S[base + j]);
            lsum += ev;
            const int p = atomicAdd(&deg[slot], 1);
            if (p < MAXD) {
                nbr_i[slot * MAXD + p] = j;
                nbr_e[slot * MAXD + p] = ev;
            }
        }
    }
    __shared__ float rs[256];
    rs[tid] = lsum;
    __syncthreads();
    for (int off = 128; off > 0; off >>= 1) {
        if (tid < off) rs[tid] += rs[tid + off];
        __syncthreads();
    }
    if (tid == 0) sumv[slot] = rs[0];
}

// ---------------------------------------------------------------------------
// k_dm: Mstat over static neighbors + dirty list (with canonical slots) +
// needh[e'] flag for events whose h rows are later consumed.
// [byte-identical to round 6]
// ---------------------------------------------------------------------------
__global__ __launch_bounds__(128) void k_dm(
    const int* __restrict__ deg, const float* __restrict__ sumv,
    const int* __restrict__ nbr_i, const float* __restrict__ nbr_e,
    const int* __restrict__ fu, const float* __restrict__ h_tab,
    float* __restrict__ Mstat, int* __restrict__ dcnt,
    int* __restrict__ dl_s, float* __restrict__ dl_q,
    int* __restrict__ needh)
{
    const int slot = blockIdx.x;
    const int e = slot >> 1;
    const int c = threadIdx.x;
    const int d = min(deg[slot], MAXD);
    const float rinv = 1.f / (sumv[slot] + 1e-7f);
    float m = -INFINITY;
    for (int j0 = 0; j0 < d; ++j0) {
        const int j = nbr_i[slot * MAXD + j0];
        if (fu[j] >= 2 * e)
            m = fmaxf(m, nbr_e[slot * MAXD + j0] * rinv * h_tab[(size_t)j * H + c]);
    }
    Mstat[slot * H + c] = m;
    for (int j0 = c; j0 < d; j0 += 128) {
        const int j = nbr_i[slot * MAXD + j0];
        const int f = fu[j];
        if (f < 2 * e) {
            const int p = atomicAdd(&dcnt[slot], 1);
            if (p < MAXDIRTY) {
                dl_s[slot * MAXDIRTY + p] = f;
                dl_q[slot * MAXDIRTY + p] = nbr_e[slot * MAXD + j0] * rinv;
            }
            needh[f >> 1] = 1;   // h row of event f/2 is consumed later
        }
    }
}

// ---------------------------------------------------------------------------
// k_ls: lam (block 0) + survival (blocks 1..SS).  [byte-identical to round 6]
// ---------------------------------------------------------------------------
__global__ __launch_bounds__(64) void k_ls(
    const int* __restrict__ u, const int* __restrict__ v, const int* __restrict__ kk,
    const int* __restrict__ u_o, const int* __restrict__ v_o,
    const float* __restrict__ d0, const float* __restrict__ d1,
    const float* __restrict__ psi, const float* __restrict__ b_om,
    float* __restrict__ lamout, float* __restrict__ svout)
{
    const int b = threadIdx.x;
    if (blockIdx.x == 0) {
        if (b < NEV) {
            const int kv = kk[b];
            const float* dk = kv ? d1 : d0;
            const float g = 0.5f * (dk[u[b]] + dk[v[b]]) + b_om[kv];
            const float ps = psi[kv];
            const float x = fminf(75.f, fmaxf(-75.f, g / ps));
            lamout[b] = ps * log1pf(expf(x));
        }
    } else {
        const int s = blockIdx.x - 1;
        const float p0 = psi[0], p1 = psi[1], bo0 = b_om[0], bo1 = b_om[1];
        const int vo = v_o[b * SS + s], uo = u_o[b * SS + s];
        float g, x;
        g = 0.5f * (d0[u[b]] + d0[vo]) + bo0; x = fminf(75.f, fmaxf(-75.f, g / p0));
        const float ru0 = p0 * log1pf(expf(x));
        g = 0.5f * (d1[u[b]] + d1[vo]) + bo1; x = fminf(75.f, fmaxf(-75.f, g / p1));
        const float ru1 = p1 * log1pf(expf(x));
        g = 0.5f * (d1[v[b]] + d1[uo]) + bo1; x = fminf(75.f, fmaxf(-75.f, g / p1));
        const float rv1 = p1 * log1pf(expf(x));
        float val = 2.f * (ru0 + ru1) + rv1;
#pragma unroll
        for (int off = 32; off > 0; off >>= 1) val += __shfl_xor(val, off);
        if (b == 0) svout[s] = val / (float)SS;
    }
}

// ---------------------------------------------------------------------------
// k_seq v5: batched event scan. Thread 0 pairs consecutive INDEPENDENT events
// (node-disjoint + no dirty read of the partner's slots); each batch of 1-2
// events (2-4 rows) runs one phase sweep with 2 barriers (3 if phase C).
// Phase B/C use in-wave shfl reductions (s=(tid>>4)&3 within the wave) over
// PADDED staging buffers: hz[4][33][8] (stride 264 = 8 mod 32 banks),
// znw[4][33][4] (stride 132 = 4 mod 32) -> every ds_read_b128 is a
// conflict-free 16-lane broadcast (round-3 lesson applied).
// ---------------------------------------------------------------------------
constexpr int KSEQ_LDS_FLOATS = 16384 + 16384 + 4 * 33 * 8 + 4 * 33 * 4 + 128; // 34480
constexpr int KSEQ_LDS_INTS   = 64 + 64 + 128 + 128 + 128 + 128 + 64 + 64 + 64 + 4; // 836
constexpr int KSEQ_LDS_BYTES  = (KSEQ_LDS_FLOATS + KSEQ_LDS_INTS) * 4;   // 141264

__global__ __launch_bounds__(512, 1) void k_seq(
    const int* __restrict__ u, const int* __restrict__ v,
    const float* __restrict__ W_S, const float* __restrict__ W_R,
    const float* __restrict__ W_t, const float* __restrict__ W_h,
    const float* __restrict__ b_h,
    const int* __restrict__ deg, const int* __restrict__ dcnt,
    const int* __restrict__ dl_s, const float* __restrict__ dl_q,
    const float* __restrict__ Mstat,
    const int* __restrict__ zsrc, const int* __restrict__ wslot,
    const float* __restrict__ dtv, const int* __restrict__ needh,
    float* __restrict__ z_out)
{
    extern __shared__ float lds[];
    float* z_upd = lds;                     // [128][128]
    float* h_upd = z_upd + 16384;           // [128][128]
    float* hz    = h_upd + 16384;           // [4][33][8]: c'=s*32+i -> [s][i][2r+{hs,z}]
    float* znw   = hz + 4 * 33 * 8;         // [4][33][4]: c'=s*32+i -> [s][i][r]
    float* dtv_l = znw + 4 * 33 * 4;        // [128]
    int*   ib    = (int*)(dtv_l + 128);
    int* ev_u_l  = ib;                      // 64
    int* ev_v_l  = ib + 64;                 // 64
    int* zsrc_l  = ib + 128;                // 128
    int* wslot_l = ib + 256;                // 128
    int* deg_l   = ib + 384;                // 128
    int* dcnt_l  = ib + 512;                // 128
    int* needh_l = ib + 640;                // 64
    int* bev_l   = ib + 704;                // 64
    int* bsz_l   = ib + 768;                // 64
    int* nb_p    = ib + 832;                // 1

    const int tid = threadIdx.x;
    // Phase-A role map: column cA, row-slot j
    const int cA = tid & 127;
    const int j  = tid >> 7;                // 0..3
    // Phase-B/C role map: chunk s within wave, column c
    const int s  = (tid >> 4) & 3;
    const int c  = (tid & 15) | ((tid >> 6) << 4);

    float wsr[32], wrr[32], whr[32];
#pragma unroll
    for (int i = 0; i < 32; ++i) {
        wsr[i] = W_S[c * H + s * 32 + i];
        wrr[i] = W_R[c * H + s * 32 + i];
        whr[i] = W_h[c * H + s * 32 + i];
    }
    const float wt_c = W_t[c];
    const float bh_c = b_h[c];

    if (tid < 64)                { ev_u_l[tid] = u[tid]; ev_v_l[tid] = v[tid]; }
    else if (tid < 192)          { const int i = tid - 64;  zsrc_l[i] = zsrc[i]; wslot_l[i] = wslot[i]; }
    else if (tid < 320)          { const int i = tid - 192; deg_l[i] = deg[i]; dcnt_l[i] = dcnt[i]; }
    else if (tid < 448)          { const int i = tid - 320; dtv_l[i] = dtv[i]; }
    else                         { needh_l[tid - 448] = needh[tid - 448]; }
    __syncthreads();

    // ---- batch scheduler (thread 0): pair consecutive independent events ----
    if (tid == 0) {
        int nb = 0, i = 0;
        while (i < NEV) {
            int sz = 1;
            if (i + 1 < NEV) {
                const int a0 = ev_u_l[i], a1 = ev_v_l[i];
                const int b0 = ev_u_l[i + 1], b1 = ev_v_l[i + 1];
                bool dep = (b0 == a0 || b0 == a1 || b1 == a0 || b1 == a1);
                if (!dep) {
                    const int w0 = wslot_l[2 * i], w1 = wslot_l[2 * i + 1];
                    for (int sd = 0; sd < 2 && !dep; ++sd) {
                        const int sl = 2 * (i + 1) + sd;
                        const int nd = min(dcnt_l[sl], MAXDIRTY);
                        for (int p = 0; p < nd; ++p) {
                            const int f = dl_s[sl * MAXDIRTY + p];
                            if (f == w0 || f == w1) { dep = true; break; }
                        }
                    }
                }
                if (!dep) sz = 2;
            }
            bev_l[nb] = i; bsz_l[nb] = sz; ++nb; i += sz;
        }
        *nb_p = nb;
    }
    __syncthreads();
    const int nb = *nb_p;

    // ---- prefetch for batch 0 ----
    float mpf = 0.f, dlq0 = 0.f, zpf = 0.f;
    int dls0 = 0;
    if (j < 2 * bsz_l[0]) {                     // bev_l[0] == 0
        const int slot = j;
        mpf  = Mstat[slot * H + cA];
        dls0 = dl_s[slot * MAXDIRTY];
        dlq0 = dl_q[slot * MAXDIRTY];
        if (zsrc_l[slot] < 0) {
            const int ev = j >> 1;
            const int node = (j & 1) ? ev_u_l[ev] : ev_v_l[ev];
            zpf = z_out[(size_t)node * H + cA];
        }
    }

    for (int m = 0; m < nb; ++m) {
        const int bev = bev_l[m], bsz = bsz_l[m];
        const int rows = 2 * bsz;

        // ---- Phase A: per-row hs (Mstat + dirty) and z, staged into hz ----
        if (j < rows) {
            const int slot = 2 * bev + j;
            float mm = mpf;
            const int nd = min(dcnt_l[slot], MAXDIRTY);
            if (nd > 0) {
                mm = fmaxf(mm, dlq0 * h_upd[dls0 * 128 + cA]);
                for (int p = 1; p < nd; ++p) {
                    const int f2 = dl_s[slot * MAXDIRTY + p];
                    const float q2 = dl_q[slot * MAXDIRTY + p];
                    mm = fmaxf(mm, q2 * h_upd[f2 * 128 + cA]);
                }
            }
            const float hs = (deg_l[slot] > 0) ? 1.f / (1.f + __expf(-mm)) : 0.f;
            const int sl = zsrc_l[slot];
            const float zv = (sl >= 0) ? z_upd[sl * 128 + cA] : zpf;
            const int base = (cA >> 5) * 264 + (cA & 31) * 8;
            hz[base + 2 * j]     = hs;
            hz[base + 2 * j + 1] = zv;
        }
        // prefetch batch m+1 (all sources immutable; overlaps bar1 + B)
        if (m + 1 < nb) {
            const int nbev = bev_l[m + 1];
            if (j < 2 * bsz_l[m + 1]) {
                const int slot = 2 * nbev + j;
                mpf  = Mstat[slot * H + cA];
                dls0 = dl_s[slot * MAXDIRTY];
                dlq0 = dl_q[slot * MAXDIRTY];
                if (zsrc_l[slot] < 0) {
                    const int ev = nbev + (j >> 1);
                    const int node = (j & 1) ? ev_u_l[ev] : ev_v_l[ev];
                    zpf = z_out[(size_t)node * H + cA];
                }
            }
        }
        __syncthreads();                       // bar1: hz ready

        // ---- Phase B: g[r][c] for up to 4 rows, in-wave chunk reduction ----
        float g0 = 0.f, g1 = 0.f, g2 = 0.f, g3 = 0.f;
        {
            const int hb = s * 264;
#pragma unroll
            for (int i = 0; i < 32; ++i) {
                const float4 f0 = *(const float4*)&hz[hb + i * 8];
                const float4 f1 = *(const float4*)&hz[hb + i * 8 + 4];
                g0 += f0.x * wsr[i] + f0.y * wrr[i];
                g1 += f0.z * wsr[i] + f0.w * wrr[i];
                g2 += f1.x * wsr[i] + f1.y * wrr[i];
                g3 += f1.z * wsr[i] + f1.w * wrr[i];
            }
        }
        g0 += __shfl_xor(g0, 16); g0 += __shfl_xor(g0, 32);
        g1 += __shfl_xor(g1, 16); g1 += __shfl_xor(g1, 32);
        g2 += __shfl_xor(g2, 16); g2 += __shfl_xor(g2, 32);
        g3 += __shfl_xor(g3, 16); g3 += __shfl_xor(g3, 32);
        if (s < rows) {                        // lane finalizes row r = s
            const int r = s;
            const int slot = 2 * bev + r;
            const int ev = bev + (r >> 1);
            const bool dup = (ev_u_l[ev] == ev_v_l[ev]);
            if (!(dup && (r & 1) == 0)) {      // duplicate rows: u-row wins
                float g = (s == 0) ? g0 : ((s == 1) ? g1 : ((s == 2) ? g2 : g3));
                g += dtv_l[slot] * wt_c;
                const float zv = 1.f / (1.f + __expf(-g));
                z_upd[wslot_l[slot] * 128 + c] = zv;
                znw[(c >> 5) * 132 + (c & 31) * 4 + r] = zv;
            }
        }
        __syncthreads();                       // bar2: z_upd/znw ready

        // ---- Phase C (rare): refresh h rows consumed by later dirty reads ----
        const bool cflag = needh_l[bev] || (bsz == 2 && needh_l[bev + 1]);
        if (cflag) {
            float h0 = 0.f, h1 = 0.f, h2 = 0.f, h3 = 0.f;
            {
                const int zb = s * 132;
#pragma unroll
                for (int i = 0; i < 32; ++i) {
                    const float4 f = *(const float4*)&znw[zb + i * 4];
                    h0 += f.x * whr[i];
                    h1 += f.y * whr[i];
                    h2 += f.z * whr[i];
                    h3 += f.w * whr[i];
                }
            }
            h0 += __shfl_xor(h0, 16); h0 += __shfl_xor(h0, 32);
            h1 += __shfl_xor(h1, 16); h1 += __shfl_xor(h1, 32);
            h2 += __shfl_xor(h2, 16); h2 += __shfl_xor(h2, 32);
            h3 += __shfl_xor(h3, 16); h3 += __shfl_xor(h3, 32);
            if (s < rows) {
                const int r = s;
                const int slot = 2 * bev + r;
                const int ev = bev + (r >> 1);
                const bool dup = (ev_u_l[ev] == ev_v_l[ev]);
                if (needh_l[ev] && !(dup && (r & 1) == 0)) {
                    const float hv = ((s == 0) ? h0 : ((s == 1) ? h1 : ((s == 2) ? h2 : h3))) + bh_c;
                    h_upd[wslot_l[slot] * 128 + c] = hv;
                }
            }
            __syncthreads();                   // bar3
        }
    }

    // ---- flush canonical slots, coalesced: lane = column ----
    for (int sl = j; sl < 128; sl += 4) {
        if (wslot_l[sl] == sl) {
            const int node = (sl & 1) ? ev_u_l[sl >> 1] : ev_v_l[sl >> 1];
            z_out[(size_t)node * H + cA] = z_upd[sl * 128 + cA];
        }
    }
}

// ---------------------------------------------------------------------------
extern "C" void kernel_launch(void* const* d_in, const int* in_sizes, int n_in,
                              void* d_out, int out_size, void* d_ws, size_t ws_size,
                              hipStream_t stream)
{
    const int*   u        = (const int*)d_in[0];
    const int*   v        = (const int*)d_in[1];
    const float* t        = (const float*)d_in[2];
    const int*   k        = (const int*)d_in[3];
    const int*   u_others = (const int*)d_in[4];
    const int*   v_others = (const int*)d_in[5];
    const float* A        = (const float*)d_in[6];
    const float* S        = (const float*)d_in[7];
    const float* emb      = (const float*)d_in[8];
    const float* lastt    = (const float*)d_in[9];
    const float* W_S      = (const float*)d_in[10];
    const float* W_R      = (const float*)d_in[11];
    const float* W_t      = (const float*)d_in[12];
    const float* W_h      = (const float*)d_in[13];
    const float* b_h      = (const float*)d_in[14];
    const float* psi      = (const float*)d_in[15];
    const float* W_om     = (const float*)d_in[16];
    const float* b_om     = (const float*)d_in[17];
    (void)in_sizes; (void)n_in; (void)out_size; (void)ws_size;

    float* wsf   = (float*)d_ws;
    float* h_tab = wsf;                           // N*H
    float* d0    = h_tab + (size_t)N * H;         // N
    float* d1    = d0 + N;                        // N
    float* sumv  = d1 + N;                        // 128
    float* nbre  = sumv + 128;                    // 128*MAXD
    float* Mstat = nbre + 128 * MAXD;             // 128*H
    float* dl_q  = Mstat + 128 * H;               // 128*MAXDIRTY
    float* dtv   = dl_q + 128 * MAXDIRTY;         // 128
    int*   deg   = (int*)(dtv + 128);             // 128
    int*   dcnt  = deg + 128;                     // 128
    int*   nbri  = dcnt + 128;                    // 128*MAXD
    int*   dl_s  = nbri + 128 * MAXD;             // 128*MAXDIRTY
    int*   fu    = dl_s + 128 * MAXDIRTY;         // N
    int*   zsrc  = fu + N;                        // 128
    int*   wslot = zsrc + 128;                    // 128
    int*   needh = wslot + 128;                   // 64

    float* out    = (float*)d_out;
    float* lamout = out;            // [64]
    float* svout  = out + NEV;      // [20]
    float* z_out  = out + NEV + SS; // [N*H]

    hipFuncSetAttribute((const void*)k_seq,
                        hipFuncAttributeMaxDynamicSharedMemorySize,
                        KSEQ_LDS_BYTES);

    k_init<<<1, 256, 0, stream>>>(u, v, t, lastt, fu, zsrc, wslot, dtv, deg, dcnt, needh);
    k_emb<<<N / RPB, 512, 0, stream>>>(emb, W_h, b_h, W_om, h_tab, z_out, d0, d1);
    k_nbr<<<128, 256, 0, stream>>>(u, v, A, S, deg, sumv, nbri, nbre);
    k_dm<<<128, 128, 0, stream>>>(deg, sumv, nbri, nbre, fu, h_tab, Mstat, dcnt, dl_s, dl_q, needh);
    k_ls<<<SS + 1, 64, 0, stream>>>(u, v, k, u_others, v_others, d0, d1, psi, b_om, lamout, svout);
    k_seq<<<1, 512, KSEQ_LDS_BYTES, stream>>>(u, v, W_S, W_R, W_t, W_h, b_h,
                                              deg, dcnt, dl_s, dl_q, Mstat,
                                              zsrc, wslot, dtv, needh, z_out);
}